// Round 1
// baseline (1269.755 us; speedup 1.0000x reference)
//
#include <hip/hip_runtime.h>

#define BB 64
#define NN 16384
#define CC 128
#define KK 24
#define OUTW (3 + 2*CC)   // 259
#define NCHUNK 16

// ---------------- k1: counts + xyz sums, per-chunk partials (no global atomics) ----
__global__ __launch_bounds__(256) void k1_cnt_xyz(
    const float* __restrict__ xyz, const int* __restrict__ labels,
    float* __restrict__ pcnt, float* __restrict__ psxyz)
{
    __shared__ float bins[4][KK][4];   // [wave][k][count,x,y,z]
    const int tid   = threadIdx.x;
    const int b     = blockIdx.x >> 4;
    const int chunk = blockIdx.x & 15;
    const int w     = tid >> 6;

    for (int i = tid; i < 4*KK*4; i += 256) ((float*)bins)[i] = 0.f;
    __syncthreads();

    const int4*   lrow = (const int4*)(labels + (size_t)b*NN);
    const float4* xrow = (const float4*)(xyz + (size_t)b*NN*3);

    int n4 = chunk*256 + tid;            // int4 index within batch, [0,4096)
    int4 l = lrow[n4];
    float4 f0 = xrow[n4*3+0], f1 = xrow[n4*3+1], f2 = xrow[n4*3+2];
    float px[4] = {f0.x, f0.w, f1.z, f2.y};
    float py[4] = {f0.y, f1.x, f1.w, f2.z};
    float pz[4] = {f0.z, f1.y, f2.x, f2.w};
    int   ls[4] = {l.x, l.y, l.z, l.w};
    #pragma unroll
    for (int j = 0; j < 4; ++j) {
        float* bb = bins[w][ls[j]];
        atomicAdd(&bb[0], 1.0f);
        atomicAdd(&bb[1], px[j]);
        atomicAdd(&bb[2], py[j]);
        atomicAdd(&bb[3], pz[j]);
    }
    __syncthreads();
    if (tid < KK*4) {
        int k = tid >> 2, j = tid & 3;
        float v = bins[0][k][j] + bins[1][k][j] + bins[2][k][j] + bins[3][k][j];
        int base = (b*NCHUNK + chunk)*KK + k;
        if (j == 0) pcnt[base] = v;
        else        psxyz[base*3 + (j-1)] = v;
    }
}

// ---------------- k2: LDS fire-and-forget atomic binning, O(1) work per element ----
// One wave per channel-PAIR (c, c+64) of one batch, coalesced float4 loads along N.
// Per element: ds_add_f32 (sum) + ds_max_i32 (max of clamped value; valid because
// the reference max is floored at 0 and nonneg floats are int-monotone).
// 4 bin replicas selected by lane&3, layout [K][4][2]: word addr = l*8+r*2+ch, so
// distinct (label%4, replica) -> distinct bank; expected ~4 lanes/bank.
__global__ __launch_bounds__(256) void k2_feat(
    const float* __restrict__ features, const int* __restrict__ labels,
    float* __restrict__ sumf, float* __restrict__ maxf)
{
    __shared__ float s_sum[4][KK][4][2];   // [wave][k][replica][ch]
    __shared__ int   s_max[4][KK][4][2];

    const int tid  = threadIdx.x;
    const int lane = tid & 63;
    const int w    = tid >> 6;
    const int wid  = blockIdx.x*4 + w;    // 0..4095
    const int b    = wid >> 6;
    const int cp   = wid & 63;            // channels cp and cp+64
    const int r2   = (lane & 3) * 2;      // replica offset (pre-scaled)

    for (int i = tid; i < 4*KK*4*2; i += 256) {
        ((float*)s_sum)[i] = 0.f;
        ((int*)  s_max)[i] = 0;
    }
    __syncthreads();

    const float4* f0 = (const float4*)(features + ((size_t)b*CC + cp)*NN);
    const float4* f1 = f0 + (size_t)64*NN/4;
    const int4*   lr = (const int4*)(labels + (size_t)b*NN);

    float* ws_sum = &s_sum[w][0][0][0];
    int*   ws_max = &s_max[w][0][0][0];

    for (int it = 0; it < NN/256; ++it) {   // 64 iterations
        int idx = it*64 + lane;
        float4 a = f0[idx];
        float4 c = f1[idx];
        int4   l = lr[idx];
        int   la[4] = {l.x, l.y, l.z, l.w};
        float va[4] = {a.x, a.y, a.z, a.w};
        float vc[4] = {c.x, c.y, c.z, c.w};
        #pragma unroll
        for (int j = 0; j < 4; ++j) {
            int base = la[j]*8 + r2;             // word index into [K][4][2]
            atomicAdd(&ws_sum[base+0], va[j]);
            atomicAdd(&ws_sum[base+1], vc[j]);
            atomicMax(&ws_max[base+0], __float_as_int(fmaxf(va[j], 0.f)));
            atomicMax(&ws_max[base+1], __float_as_int(fmaxf(vc[j], 0.f)));
        }
    }
    __syncthreads();

    // fold 4 replicas; 48 outputs per wave (24 labels x 2 channels)
    if (lane < 48) {
        int k  = lane >> 1;
        int ch = lane & 1;
        float s = 0.f, m = 0.f;
        #pragma unroll
        for (int rr = 0; rr < 4; ++rr) {
            s += s_sum[w][k][rr][ch];
            m  = fmaxf(m, __int_as_float(s_max[w][k][rr][ch]));
        }
        size_t o = (size_t)b*KK*CC + (size_t)k*CC + cp + (ch ? 64 : 0);
        sumf[o] = s;
        maxf[o] = m;
    }
}

// ---------------- k3: fold partials + epilogue --------------------------------------
__global__ __launch_bounds__(128) void k3_final(
    const float* __restrict__ pcnt, const float* __restrict__ psxyz,
    const float* __restrict__ sumf, const float* __restrict__ maxf,
    float* __restrict__ out)
{
    const int bk = blockIdx.x;       // b*KK + k
    const int b  = bk / KK, k = bk % KK;
    const int c  = threadIdx.x;      // 0..127

    float cn = 0.f;
    #pragma unroll
    for (int ch = 0; ch < NCHUNK; ++ch) cn += pcnt[(b*NCHUNK + ch)*KK + k];
    float inv = 1.0f / fmaxf(cn, 1.0f);

    float* orow = out + (size_t)bk * OUTW;
    if (c < 3) {
        float s = 0.f;
        #pragma unroll
        for (int ch = 0; ch < NCHUNK; ++ch) s += psxyz[((b*NCHUNK + ch)*KK + k)*3 + c];
        orow[c] = s * inv;
    }
    float s    = sumf[(size_t)bk*CC + c];
    float mean = s * inv;
    orow[3 + c] = mean;
    float m    = maxf[(size_t)bk*CC + c];              // = max(0, seg_max)
    orow[3 + CC + c] = (cn > 0.f) ? fmaxf(m - mean, 0.f) : 0.f;
}

extern "C" void kernel_launch(void* const* d_in, const int* in_sizes, int n_in,
                              void* d_out, int out_size, void* d_ws, size_t ws_size,
                              hipStream_t stream) {
    const float* xyz      = (const float*)d_in[0];
    const float* features = (const float*)d_in[1];
    const int*   labels   = (const int*)d_in[2];
    float* out = (float*)d_out;

    char* ws = (char*)d_ws;
    const size_t SZ_SUMF = (size_t)BB*KK*CC*4;        // 786432 B
    const size_t SZ_PCNT = (size_t)BB*NCHUNK*KK*4;    // 98304 B
    float* sumf  = (float*)ws;
    float* maxf  = (float*)(ws + SZ_SUMF);
    float* pcnt  = (float*)(ws + 2*SZ_SUMF);
    float* psxyz = (float*)(ws + 2*SZ_SUMF + SZ_PCNT);

    k1_cnt_xyz<<<BB*NCHUNK, 256, 0, stream>>>(xyz, labels, pcnt, psxyz);
    k2_feat<<<BB*CC/2/4, 256, 0, stream>>>(features, labels, sumf, maxf);
    k3_final<<<BB*KK, 128, 0, stream>>>(pcnt, psxyz, sumf, maxf, out);
}

// Round 3
// 822.860 us; speedup vs baseline: 1.5431x; 1.5431x over previous
//
#include <hip/hip_runtime.h>

#define BB 64
#define NN 16384
#define CC 128
#define KK 24
#define OUTW (3 + 2*CC)   // 259
#define NCHUNK 16

// k2 tiling
#define CHUNKS    8                 // blocks per batch
#define PTS_BLK   (NN/CHUNKS)       // 2048 points per block
#define TILE_PTS  64                // points per LDS tile
#define TILES     (PTS_BLK/TILE_PTS)// 32 tiles per block
#define SLOTS     (TILE_PTS/4)      // 16 float4 per channel row
#define RSTRIDE   17                // padded row stride in float4 slots (bank spread)

// ---------------- k1: zero-init accumulators + counts + xyz sums -------------------
__global__ __launch_bounds__(256) void k1_cnt_xyz(
    const float* __restrict__ xyz, const int* __restrict__ labels,
    float* __restrict__ pcnt, float* __restrict__ psxyz, float4* __restrict__ zbuf)
{
    __shared__ float bins[4][KK][4];   // [wave][k][count,x,y,z]
    const int tid   = threadIdx.x;
    const int b     = blockIdx.x >> 4;
    const int chunk = blockIdx.x & 15;
    const int w     = tid >> 6;

    // zero sumf+maxf (98304 float4) before k2 accumulates into them
    const int gid = blockIdx.x*256 + tid;
    if (gid < 2*(BB*KK*CC/4)) zbuf[gid] = make_float4(0.f, 0.f, 0.f, 0.f);

    for (int i = tid; i < 4*KK*4; i += 256) ((float*)bins)[i] = 0.f;
    __syncthreads();

    const int4*   lrow = (const int4*)(labels + (size_t)b*NN);
    const float4* xrow = (const float4*)(xyz + (size_t)b*NN*3);

    int n4 = chunk*256 + tid;            // int4 index within batch, [0,4096)
    int4 l = lrow[n4];
    float4 f0 = xrow[n4*3+0], f1 = xrow[n4*3+1], f2 = xrow[n4*3+2];
    float px[4] = {f0.x, f0.w, f1.z, f2.y};
    float py[4] = {f0.y, f1.x, f1.w, f2.z};
    float pz[4] = {f0.z, f1.y, f2.x, f2.w};
    int   ls[4] = {l.x, l.y, l.z, l.w};
    #pragma unroll
    for (int j = 0; j < 4; ++j) {
        float* bb = bins[w][ls[j]];
        atomicAdd(&bb[0], 1.0f);
        atomicAdd(&bb[1], px[j]);
        atomicAdd(&bb[2], py[j]);
        atomicAdd(&bb[3], pz[j]);
    }
    __syncthreads();
    if (tid < KK*4) {
        int k = tid >> 2, j = tid & 3;
        float v = bins[0][k][j] + bins[1][k][j] + bins[2][k][j] + bins[3][k][j];
        int base = (b*NCHUNK + chunk)*KK + k;
        if (j == 0) pcnt[base] = v;
        else        psxyz[base*3 + (j-1)] = v;
    }
}

// ---------------- k2: LDS tile transpose + scalar-label register binning -----------
// Block = 4 waves, handles 2048 points of one batch. Per tile: coalesced float4 row
// loads -> padded LDS tile [128ch][17 slots]; compute reads COLUMNS via ds_read_b128
// (lane = channel, bank-spread via stride-17), label per point is wave-uniform
// (readfirstlane) -> scalar branch tree -> statically-indexed register accumulators.
// O(1) work per element, no atomics/RMW in the hot loop. All accumulator indices are
// compile-time constants (incl. the fold) so s0/s1/m0/m1 stay in VGPRs (rule #20).
#define ACC(k) { s0[k] += fa; m0[k] = fmaxf(m0[k], fa); s1[k] += fb; m1[k] = fmaxf(m1[k], fb); }
#define TREE(lv, av, bv) { \
    const int l = (lv); const float fa = (av), fb = (bv); \
    if (l < 12) { \
      if (l < 6) { \
        if (l < 3) { if (l < 1) ACC(0) else if (l < 2) ACC(1) else ACC(2) } \
        else       { if (l < 4) ACC(3) else if (l < 5) ACC(4) else ACC(5) } \
      } else { \
        if (l < 9) { if (l < 7) ACC(6) else if (l < 8) ACC(7) else ACC(8) } \
        else       { if (l < 10) ACC(9) else if (l < 11) ACC(10) else ACC(11) } \
      } \
    } else { \
      if (l < 18) { \
        if (l < 15) { if (l < 13) ACC(12) else if (l < 14) ACC(13) else ACC(14) } \
        else        { if (l < 16) ACC(15) else if (l < 17) ACC(16) else ACC(17) } \
      } else { \
        if (l < 21) { if (l < 19) ACC(18) else if (l < 20) ACC(19) else ACC(20) } \
        else        { if (l < 22) ACC(21) else if (l < 23) ACC(22) else ACC(23) } \
      } \
    } \
  }

__global__ __launch_bounds__(256, 2) void k2_feat(
    const float* __restrict__ features, const int* __restrict__ labels,
    float* __restrict__ sumf, float* __restrict__ maxf)
{
    __shared__ float4 tile[CC*RSTRIDE];   // 128*17*16B = 34816 B
    __shared__ int4   labs4[SLOTS];       // 64 labels = 16 int4

    const int tid  = threadIdx.x;
    const int lane = tid & 63;
    const int w    = tid >> 6;
    const int b     = blockIdx.x >> 3;    // 64 batches x 8 chunks
    const int chunk = blockIdx.x & 7;
    const int n0_4  = chunk * (PTS_BLK/4);

    const float4* fsrc = (const float4*)features + (size_t)b*CC*(NN/4);
    const int4*   lsrc = (const int4*)(labels + (size_t)b*NN);

    float s0[KK], s1[KK], m0[KK], m1[KK];
    #pragma unroll
    for (int k = 0; k < KK; ++k) { s0[k]=0.f; s1[k]=0.f; m0[k]=0.f; m1[k]=0.f; }

    #pragma unroll 1
    for (int t = 0; t < TILES; ++t) {
        const int nb4 = n0_4 + t*SLOTS;
        // ---- load phase: coalesced rows -> padded LDS ----
        #pragma unroll
        for (int p = 0; p < 8; ++p) {
            int i  = p*256 + tid;         // 0..2047
            int c  = i >> 4;              // channel row 0..127
            int n4 = i & 15;              // slot 0..15
            tile[c*RSTRIDE + n4] = fsrc[(size_t)c*(NN/4) + nb4 + n4];
        }
        if (tid < SLOTS) labs4[tid] = lsrc[nb4 + tid];
        __syncthreads();

        // ---- compute phase: wave w owns point-groups w*4..w*4+3 ----
        #pragma unroll 1
        for (int g = 0; g < 4; ++g) {
            const int p4 = w*4 + g;                   // float4 point-group in tile
            int4   lq = labs4[p4];                    // broadcast read
            float4 va = tile[lane*RSTRIDE + p4];      // ch = lane, 4 points
            float4 vb = tile[(lane+64)*RSTRIDE + p4]; // ch = lane+64
            int l0 = __builtin_amdgcn_readfirstlane(lq.x);
            int l1 = __builtin_amdgcn_readfirstlane(lq.y);
            int l2 = __builtin_amdgcn_readfirstlane(lq.z);
            int l3 = __builtin_amdgcn_readfirstlane(lq.w);
            TREE(l0, va.x, vb.x)
            TREE(l1, va.y, vb.y)
            TREE(l2, va.z, vb.z)
            TREE(l3, va.w, vb.w)
        }
        __syncthreads();
    }

    // ---- fold: global atomics (zero-inited by k1); FULLY UNROLLED so the
    // accumulator arrays are only ever statically indexed (stay in VGPRs) ----
    float* sp = sumf + (size_t)b*KK*CC;
    int*   mp = (int*)(maxf + (size_t)b*KK*CC);
    #pragma unroll
    for (int k = 0; k < KK; ++k) {
        atomicAdd(&sp[k*CC + lane],      s0[k]);
        atomicAdd(&sp[k*CC + 64 + lane], s1[k]);
        atomicMax(&mp[k*CC + lane],      __float_as_int(m0[k]));   // vals >= 0
        atomicMax(&mp[k*CC + 64 + lane], __float_as_int(m1[k]));
    }
}

// ---------------- k3: fold partials + epilogue --------------------------------------
__global__ __launch_bounds__(128) void k3_final(
    const float* __restrict__ pcnt, const float* __restrict__ psxyz,
    const float* __restrict__ sumf, const float* __restrict__ maxf,
    float* __restrict__ out)
{
    const int bk = blockIdx.x;       // b*KK + k
    const int b  = bk / KK, k = bk % KK;
    const int c  = threadIdx.x;      // 0..127

    float cn = 0.f;
    #pragma unroll
    for (int ch = 0; ch < NCHUNK; ++ch) cn += pcnt[(b*NCHUNK + ch)*KK + k];
    float inv = 1.0f / fmaxf(cn, 1.0f);

    float* orow = out + (size_t)bk * OUTW;
    if (c < 3) {
        float s = 0.f;
        #pragma unroll
        for (int ch = 0; ch < NCHUNK; ++ch) s += psxyz[((b*NCHUNK + ch)*KK + k)*3 + c];
        orow[c] = s * inv;
    }
    float s    = sumf[(size_t)bk*CC + c];
    float mean = s * inv;
    orow[3 + c] = mean;
    float m    = maxf[(size_t)bk*CC + c];              // = max(0, seg_max)
    orow[3 + CC + c] = (cn > 0.f) ? fmaxf(m - mean, 0.f) : 0.f;
}

extern "C" void kernel_launch(void* const* d_in, const int* in_sizes, int n_in,
                              void* d_out, int out_size, void* d_ws, size_t ws_size,
                              hipStream_t stream) {
    const float* xyz      = (const float*)d_in[0];
    const float* features = (const float*)d_in[1];
    const int*   labels   = (const int*)d_in[2];
    float* out = (float*)d_out;

    char* ws = (char*)d_ws;
    const size_t SZ_SUMF = (size_t)BB*KK*CC*4;        // 786432 B
    const size_t SZ_PCNT = (size_t)BB*NCHUNK*KK*4;    // 98304 B
    float* sumf  = (float*)ws;
    float* maxf  = (float*)(ws + SZ_SUMF);
    float* pcnt  = (float*)(ws + 2*SZ_SUMF);
    float* psxyz = (float*)(ws + 2*SZ_SUMF + SZ_PCNT);

    k1_cnt_xyz<<<BB*NCHUNK, 256, 0, stream>>>(xyz, labels, pcnt, psxyz, (float4*)ws);
    k2_feat<<<BB*CHUNKS, 256, 0, stream>>>(features, labels, sumf, maxf);
    k3_final<<<BB*KK, 128, 0, stream>>>(pcnt, psxyz, sumf, maxf, out);
}